// Round 5
// baseline (453.108 us; speedup 1.0000x reference)
//
#include <hip/hip_runtime.h>
#include <hip/hip_bf16.h>

#define BB 4
#define TT 2048
#define DD 1024
#define HH 16
#define HD 64
#define MM (BB*TT)   // 8192

typedef __attribute__((ext_vector_type(8))) _Float16 f16x8;
typedef __attribute__((ext_vector_type(4))) _Float16 f16x4;
typedef __attribute__((ext_vector_type(4))) float f32x4;

// (1/sqrt(64)) * log2(e) — folded into Q at projection time
#define QSCALE 0.18033688011112042f

static __device__ __forceinline__ void gload_lds16(const void* g, void* l) {
  __builtin_amdgcn_global_load_lds((const __attribute__((address_space(1))) void*)g,
                                   (__attribute__((address_space(3))) void*)l, 16, 0, 0);
}

// ---------------- fp32 -> fp16 conversion, 8 elems/thread ----------------
__global__ __launch_bounds__(256) void cvt_f16(const float* __restrict__ in,
                                               _Float16* __restrict__ out, int n8) {
  int i = blockIdx.x * 256 + threadIdx.x;
  if (i >= n8) return;
  const f32x4* p = (const f32x4*)in;
  f32x4 a = p[2*i];
  f32x4 b = p[2*i+1];
  f16x8 r;
  r[0]=(_Float16)a[0]; r[1]=(_Float16)a[1]; r[2]=(_Float16)a[2]; r[3]=(_Float16)a[3];
  r[4]=(_Float16)b[0]; r[5]=(_Float16)b[1]; r[6]=(_Float16)b[2]; r[7]=(_Float16)b[3];
  *(f16x8*)(out + (size_t)8*i) = r;
}

// ------------- W[k][n] fp32 -> Wt[n][k] fp16 (1024x1024), z picks matrix -------------
__global__ __launch_bounds__(256) void transpose_cvt(
    const float* __restrict__ W0, const float* __restrict__ W1,
    const float* __restrict__ W2, const float* __restrict__ W3,
    _Float16* __restrict__ O0, _Float16* __restrict__ O1,
    _Float16* __restrict__ O2, _Float16* __restrict__ O3) {
  const float* W; _Float16* O;
  switch (blockIdx.z) {
    case 0: W = W0; O = O0; break;
    case 1: W = W1; O = O1; break;
    case 2: W = W2; O = O2; break;
    default: W = W3; O = O3; break;
  }
  __shared__ float tile[32][33];
  int bx = blockIdx.x * 32, by = blockIdx.y * 32;
  int tx = threadIdx.x, ty = threadIdx.y;   // (32, 8)
#pragma unroll
  for (int i = 0; i < 4; i++)
    tile[ty + 8*i][tx] = W[(size_t)(by + ty + 8*i) * DD + bx + tx];
  __syncthreads();
#pragma unroll
  for (int i = 0; i < 4; i++)
    O[(size_t)(bx + ty + 8*i) * DD + by + tx] = (_Float16)tile[tx][ty + 8*i];
}

// ---------------- GEMM: C[M][N] = A[M][K] * Bt[N][K]^T + bias ----------------
// 128x128 tile, BK=32, 4 waves (2x2 of 64x64), 16x16x32 fp16 MFMA.
// mode: 0 = fp16 plain (K), 1 = fp16 * QSCALE (Q), 2 = fp16 V^T per-head
//       ( out[((b*16+h)*64+d)*2048 + t] ), 3 = f32 plain (proj)
static __device__ __forceinline__ void gemm_body(
    const _Float16* __restrict__ A, const _Float16* __restrict__ Bt,
    const float* __restrict__ bias, void* __restrict__ Cv, int mode) {
  const int K = 1024, N = 1024;
  __shared__ __align__(16) _Float16 Alds[128*32];
  __shared__ __align__(16) _Float16 Blds[128*32];
  int tid = threadIdx.x;
  int wid = tid >> 6, lane = tid & 63;
  int m0 = blockIdx.y * 128, n0 = blockIdx.x * 128;
  int wr = wid >> 1, wc = wid & 1;
  int lr = lane & 15, lk = lane >> 4;

  f32x4 zf = {0.f, 0.f, 0.f, 0.f};
  f32x4 acc[4][4];
#pragma unroll
  for (int m = 0; m < 4; m++)
#pragma unroll
    for (int n = 0; n < 4; n++) acc[m][n] = zf;

  int c0 = wid * 2;
  int srow = c0 * 16 + (lane >> 2);
  int skc  = (lane & 3) * 8;
  const _Float16* gA0 = A  + (size_t)(m0 + srow) * K + skc;
  const _Float16* gA1 = gA0 + 16 * K;
  const _Float16* gB0 = Bt + (size_t)(n0 + srow) * K + skc;
  const _Float16* gB1 = gB0 + 16 * K;
  _Float16* lA0 = Alds + c0 * 512;
  _Float16* lA1 = Alds + (c0 + 1) * 512;
  _Float16* lB0 = Blds + c0 * 512;
  _Float16* lB1 = Blds + (c0 + 1) * 512;

  for (int k0 = 0; k0 < K; k0 += 32) {
    __syncthreads();
    gload_lds16(gA0 + k0, lA0);
    gload_lds16(gA1 + k0, lA1);
    gload_lds16(gB0 + k0, lB0);
    gload_lds16(gB1 + k0, lB1);
    __syncthreads();
    f16x8 af[4], bf[4];
#pragma unroll
    for (int m = 0; m < 4; m++)
      af[m] = *(const f16x8*)&Alds[(wr*64 + m*16 + lr)*32 + lk*8];
#pragma unroll
    for (int n = 0; n < 4; n++)
      bf[n] = *(const f16x8*)&Blds[(wc*64 + n*16 + lr)*32 + lk*8];
#pragma unroll
    for (int m = 0; m < 4; m++)
#pragma unroll
      for (int n = 0; n < 4; n++)
        acc[m][n] = __builtin_amdgcn_mfma_f32_16x16x32_f16(af[m], bf[n], acc[m][n], 0, 0, 0);
  }

  // epilogue: C/D layout col = lane&15, row = (lane>>4)*4 + r
#pragma unroll
  for (int n = 0; n < 4; n++) {
    int col = n0 + wc*64 + n*16 + lr;
    float bs = bias[col];
#pragma unroll
    for (int m = 0; m < 4; m++) {
      int rowg = m0 + wr*64 + m*16 + lk*4;
      if (mode == 2) {
        int b = rowg >> 11, t = rowg & 2047;
        size_t idx = ((size_t)(b*1024 + col) << 11) + t;
        f16x4 pk;
#pragma unroll
        for (int r = 0; r < 4; r++) pk[r] = (_Float16)(acc[m][n][r] + bs);
        *(f16x4*)&((_Float16*)Cv)[idx] = pk;
      } else if (mode == 3) {
#pragma unroll
        for (int r = 0; r < 4; r++)
          ((float*)Cv)[(size_t)(rowg + r) * N + col] = acc[m][n][r] + bs;
      } else if (mode == 1) {
#pragma unroll
        for (int r = 0; r < 4; r++)
          ((_Float16*)Cv)[(size_t)(rowg + r) * N + col] =
              (_Float16)((acc[m][n][r] + bs) * QSCALE);
      } else {
#pragma unroll
        for (int r = 0; r < 4; r++)
          ((_Float16*)Cv)[(size_t)(rowg + r) * N + col] = (_Float16)(acc[m][n][r] + bs);
      }
    }
  }
}

__global__ __launch_bounds__(256) void gemm_qkv(
    const _Float16* __restrict__ X,
    const _Float16* __restrict__ WqT, const _Float16* __restrict__ WkT,
    const _Float16* __restrict__ WvT,
    const float* __restrict__ bq, const float* __restrict__ bk,
    const float* __restrict__ bv,
    _Float16* __restrict__ Qo, _Float16* __restrict__ Ko, _Float16* __restrict__ Vto) {
  const _Float16* Bt; const float* bias; _Float16* C; int mode;
  if (blockIdx.z == 0)      { Bt = WqT; bias = bq; C = Qo;  mode = 1; }
  else if (blockIdx.z == 1) { Bt = WkT; bias = bk; C = Ko;  mode = 0; }
  else                      { Bt = WvT; bias = bv; C = Vto; mode = 2; }
  gemm_body(X, Bt, bias, C, mode);
}

__global__ __launch_bounds__(256) void gemm_proj(
    const _Float16* __restrict__ Ain, const _Float16* __restrict__ WpT,
    const float* __restrict__ bp, float* __restrict__ out) {
  gemm_body(Ain, WpT, bp, out, 3);
}

// ---------------- causal flash attention ----------------
// grid (16, 64), 256 threads = 4 waves; block owns one 128-row q-tile (wave: 32
// rows = 2 frags). KV tiles of 64, double-buffered; K and V^T both staged via
// global_load_lds + XOR chunk swizzle (identical proven mechanics).
__global__ __launch_bounds__(256, 3) void attn_fwd(
    const _Float16* __restrict__ Q, const _Float16* __restrict__ Kg,
    const _Float16* __restrict__ Vt, _Float16* __restrict__ O) {
  // K: [buf][row j 0..63][64], LDS[row][c] = K[row][c ^ (row&7)]
  __shared__ __align__(16) _Float16 Klds[2*4096];
  // V^T: [buf][row d 0..63][64], LDS[d][c] = V^T[d][c ^ (d&7)]
  __shared__ __align__(16) _Float16 Vlds[2*4096];
  // P: per-wave [32][72]
  __shared__ __align__(16) _Float16 Plds[4*32*72];

  const int tid = threadIdx.x;
  const int wid = tid >> 6, lane = tid & 63;
  const int lr = lane & 15, lk = lane >> 4;
  const int bh = blockIdx.y, b = bh >> 4, h = bh & 15;
  const size_t base  = (size_t)b * TT * DD + h * HD;   // Q/K/O layout [B,T,D]
  const size_t vbase = (size_t)bh * HD * TT;           // V^T layout [B,H,D_h,T]

  // staging: wave w covers rows 16w..16w+15 (2 calls of 8 rows);
  // lane L -> row (L>>3), lds chunk L&7, global chunk (L&7)^(L>>3).
  const int krow  = 16*wid + (lane >> 3);
  const int kchnk = ((lane & 7) ^ (lane >> 3)) * 8;
  const int kg0 = krow*DD + kchnk, kg1 = kg0 + 8*DD;
  const int vg0 = krow*TT + kchnk, vg1 = vg0 + 8*TT;
  const int kl0 = 16*wid*64,       kl1 = kl0 + 8*64;

  _Float16* Pw = Plds + wid*32*72;

  const int qt = blockIdx.x;
  const int jmax = 2*qt + 1;

  // Q fragments (pre-scaled by QSCALE at projection time)
  f16x8 qf[2][2];
#pragma unroll
  for (int t = 0; t < 2; ++t) {
    const size_t qr = base + (size_t)(qt*128 + wid*32 + t*16 + lr) * DD;
#pragma unroll
    for (int hh2 = 0; hh2 < 2; ++hh2)
      qf[t][hh2] = *(const f16x8*)&Q[qr + hh2*32 + lk*8];
  }

  f32x4 zf = {0.f, 0.f, 0.f, 0.f};
  f32x4 o[2][4];
  float m[2][4], l[2][4];
#pragma unroll
  for (int t = 0; t < 2; ++t)
#pragma unroll
    for (int f = 0; f < 4; ++f) o[t][f] = zf;
#pragma unroll
  for (int t = 0; t < 2; ++t)
#pragma unroll
    for (int r = 0; r < 4; ++r) { m[t][r] = -1e30f; l[t][r] = 0.f; }

  // ---- prologue: stage tile 0 into buf 0 ----
  gload_lds16(Kg + base + kg0, Klds + kl0);
  gload_lds16(Kg + base + kg1, Klds + kl1);
  gload_lds16(Vt + vbase + vg0, Vlds + kl0);
  gload_lds16(Vt + vbase + vg1, Vlds + kl1);
  __syncthreads();

  int bsel = 0;
  for (int jt = 0; jt <= jmax; ++jt) {
    if (jt < jmax) {   // issue next-tile async loads into alternate buffers
      const size_t kb = base + (size_t)(jt+1) * 64 * DD;
      const size_t vb = vbase + (size_t)(jt+1) * 64;
      _Float16* kd = Klds + (bsel^1)*4096;
      _Float16* vd = Vlds + (bsel^1)*4096;
      gload_lds16(Kg + kb + kg0, kd + kl0);
      gload_lds16(Kg + kb + kg1, kd + kl1);
      gload_lds16(Vt + vb + vg0, vd + kl0);
      gload_lds16(Vt + vb + vg1, vd + kl1);
    }

    // ---- QK^T ----
    const _Float16* Kb = Klds + bsel*4096;
    f32x4 s[2][4];
    __builtin_amdgcn_s_setprio(1);
#pragma unroll
    for (int f = 0; f < 4; ++f) {
      const int row = 16*f + lr;
      f16x8 kf0 = *(const f16x8*)&Kb[row*64 + ((lk    ) ^ (lr & 7))*8];
      f16x8 kf1 = *(const f16x8*)&Kb[row*64 + ((lk + 4) ^ (lr & 7))*8];
#pragma unroll
      for (int t = 0; t < 2; ++t) {
        f32x4 z = zf;
        z = __builtin_amdgcn_mfma_f32_16x16x32_f16(qf[t][0], kf0, z, 0, 0, 0);
        z = __builtin_amdgcn_mfma_f32_16x16x32_f16(qf[t][1], kf1, z, 0, 0, 0);
        s[t][f] = z;
      }
    }
    __builtin_amdgcn_s_setprio(0);

    // ---- causal mask (Q pre-scaled; mask is a pure select) ----
#pragma unroll
    for (int t = 0; t < 2; ++t) {
      const int qmin = qt*128 + wid*32 + t*16;
      if (64*jt + 64 > qmin) {
#pragma unroll
        for (int f = 0; f < 4; ++f)
#pragma unroll
          for (int r = 0; r < 4; ++r) {
            int jg = 64*jt + 16*f + lr;
            int qg = qmin + lk*4 + r;
            if (jg > qg) s[t][f][r] = -1e30f;
          }
      }
    }

    // ---- online softmax with defer-max (skip rescale unless max grew > 8) ----
    float vmax[2][4];
    bool grow = false;
#pragma unroll
    for (int t = 0; t < 2; ++t)
#pragma unroll
      for (int r = 0; r < 4; ++r) {
        float v = fmaxf(fmaxf(s[t][0][r], s[t][1][r]), fmaxf(s[t][2][r], s[t][3][r]));
        v = fmaxf(v, __shfl_xor(v, 1));
        v = fmaxf(v, __shfl_xor(v, 2));
        v = fmaxf(v, __shfl_xor(v, 4));
        v = fmaxf(v, __shfl_xor(v, 8));
        vmax[t][r] = v;
        grow = grow || (v > m[t][r] + 8.f);
      }
    const bool anygrow = (__ballot(grow) != 0ull);

#pragma unroll
    for (int t = 0; t < 2; ++t) {
#pragma unroll
      for (int r = 0; r < 4; ++r) {
        float alpha = 1.f;
        if (anygrow) {
          float mn = fmaxf(m[t][r], vmax[t][r]);
          alpha = exp2f(m[t][r] - mn);
          m[t][r] = mn;
        }
        float sum = 0.f;
#pragma unroll
        for (int f = 0; f < 4; ++f) {
          float p = exp2f(s[t][f][r] - m[t][r]);
          s[t][f][r] = p;
          sum += p;
        }
        sum += __shfl_xor(sum, 1);
        sum += __shfl_xor(sum, 2);
        sum += __shfl_xor(sum, 4);
        sum += __shfl_xor(sum, 8);
        l[t][r] = l[t][r] * alpha + sum;
        if (anygrow) {
#pragma unroll
          for (int f = 0; f < 4; ++f) o[t][f][r] *= alpha;
        }
      }
      // P -> per-wave LDS (C-layout -> A-frag layout)
#pragma unroll
      for (int f = 0; f < 4; ++f)
#pragma unroll
        for (int r = 0; r < 4; ++r)
          Pw[(t*16 + lk*4 + r)*72 + f*16 + lr] = (_Float16)s[t][f][r];
    }

    // ---- P A-frags ----
    f16x8 pa[2][2];
#pragma unroll
    for (int t = 0; t < 2; ++t)
#pragma unroll
      for (int hh2 = 0; hh2 < 2; ++hh2)
        pa[t][hh2] = *(const f16x8*)&Pw[(t*16 + lr)*72 + hh2*32 + lk*8];

    // ---- O += P V  (V B-frags mirror the K reads) ----
    const _Float16* Vb = Vlds + bsel*4096;
    __builtin_amdgcn_s_setprio(1);
#pragma unroll
    for (int f = 0; f < 4; ++f) {
      const int row = 16*f + lr;   // d index
      f16x8 vf0 = *(const f16x8*)&Vb[row*64 + ((lk    ) ^ (lr & 7))*8];
      f16x8 vf1 = *(const f16x8*)&Vb[row*64 + ((lk + 4) ^ (lr & 7))*8];
#pragma unroll
      for (int t = 0; t < 2; ++t) {
        o[t][f] = __builtin_amdgcn_mfma_f32_16x16x32_f16(pa[t][0], vf0, o[t][f], 0, 0, 0);
        o[t][f] = __builtin_amdgcn_mfma_f32_16x16x32_f16(pa[t][1], vf1, o[t][f], 0, 0, 0);
      }
    }
    __builtin_amdgcn_s_setprio(0);

    __syncthreads();   // drains async gloads into buf^1 + all LDS reads
    bsel ^= 1;
  }

  // ---- finalize + write O ----
#pragma unroll
  for (int t = 0; t < 2; ++t) {
    float inv[4];
#pragma unroll
    for (int r = 0; r < 4; ++r) inv[r] = 1.f / l[t][r];
#pragma unroll
    for (int f = 0; f < 4; ++f) {
      int d = 16*f + lr;
#pragma unroll
      for (int r = 0; r < 4; ++r) {
        int qg = qt*128 + wid*32 + t*16 + lk*4 + r;
        O[base + (size_t)qg * DD + d] = (_Float16)(o[t][f][r] * inv[r]);
      }
    }
  }
}

extern "C" void kernel_launch(void* const* d_in, const int* in_sizes, int n_in,
                              void* d_out, int out_size, void* d_ws, size_t ws_size,
                              hipStream_t stream) {
  const float* x  = (const float*)d_in[0];
  const float* Wq = (const float*)d_in[1];
  const float* bq = (const float*)d_in[2];
  const float* Wk = (const float*)d_in[3];
  const float* bk = (const float*)d_in[4];
  const float* Wv = (const float*)d_in[5];
  const float* bv = (const float*)d_in[6];
  const float* Wp = (const float*)d_in[7];
  const float* bp = (const float*)d_in[8];
  float* out = (float*)d_out;

  const size_t XN = (size_t)MM * DD;   // 8,388,608
  const size_t WN = (size_t)DD * DD;   // 1,048,576
  _Float16* ws  = (_Float16*)d_ws;
  _Float16* Xb  = ws;                  // also reused as attention output (Ab)
  _Float16* WqT = ws + XN;
  _Float16* WkT = WqT + WN;
  _Float16* WvT = WkT + WN;
  _Float16* WpT = WvT + WN;
  _Float16* Qb  = WpT + WN;
  _Float16* Kb  = Qb + XN;
  _Float16* Vbt = Kb + XN;             // V^T [B,H,HD,T]
  _Float16* Ab  = Xb;

  cvt_f16<<<dim3((unsigned)(XN/8/256)), 256, 0, stream>>>(x, Xb, (int)(XN/8));
  transpose_cvt<<<dim3(32, 32, 4), dim3(32, 8), 0, stream>>>(Wq, Wk, Wv, Wp,
                                                             WqT, WkT, WvT, WpT);
  gemm_qkv<<<dim3(8, 64, 3), 256, 0, stream>>>(Xb, WqT, WkT, WvT, bq, bk, bv,
                                               Qb, Kb, Vbt);
  attn_fwd<<<dim3(16, 64), 256, 0, stream>>>(Qb, Kb, Vbt, Ab);
  gemm_proj<<<dim3(8, 64), 256, 0, stream>>>(Ab, WpT, bp, out);
}

// Round 6
// 352.366 us; speedup vs baseline: 1.2859x; 1.2859x over previous
//
#include <hip/hip_runtime.h>
#include <hip/hip_bf16.h>

#define BB 4
#define TT 2048
#define DD 1024
#define HH 16
#define HD 64
#define MM (BB*TT)   // 8192

typedef __attribute__((ext_vector_type(8))) _Float16 f16x8;
typedef __attribute__((ext_vector_type(4))) _Float16 f16x4;
typedef __attribute__((ext_vector_type(4))) float f32x4;

// (1/sqrt(64)) * log2(e) — folded into Q at projection time
#define QSCALE 0.18033688011112042f

static __device__ __forceinline__ void gload_lds16(const void* g, void* l) {
  __builtin_amdgcn_global_load_lds((const __attribute__((address_space(1))) void*)g,
                                   (__attribute__((address_space(3))) void*)l, 16, 0, 0);
}

// ---------------- fp32 -> fp16 conversion, 8 elems/thread ----------------
__global__ __launch_bounds__(256) void cvt_f16(const float* __restrict__ in,
                                               _Float16* __restrict__ out, int n8) {
  int i = blockIdx.x * 256 + threadIdx.x;
  if (i >= n8) return;
  const f32x4* p = (const f32x4*)in;
  f32x4 a = p[2*i];
  f32x4 b = p[2*i+1];
  f16x8 r;
  r[0]=(_Float16)a[0]; r[1]=(_Float16)a[1]; r[2]=(_Float16)a[2]; r[3]=(_Float16)a[3];
  r[4]=(_Float16)b[0]; r[5]=(_Float16)b[1]; r[6]=(_Float16)b[2]; r[7]=(_Float16)b[3];
  *(f16x8*)(out + (size_t)8*i) = r;
}

// ------------- W[k][n] fp32 -> Wt[n][k] fp16 (1024x1024), z picks matrix -------------
__global__ __launch_bounds__(256) void transpose_cvt(
    const float* __restrict__ W0, const float* __restrict__ W1,
    const float* __restrict__ W2, const float* __restrict__ W3,
    _Float16* __restrict__ O0, _Float16* __restrict__ O1,
    _Float16* __restrict__ O2, _Float16* __restrict__ O3) {
  const float* W; _Float16* O;
  switch (blockIdx.z) {
    case 0: W = W0; O = O0; break;
    case 1: W = W1; O = O1; break;
    case 2: W = W2; O = O2; break;
    default: W = W3; O = O3; break;
  }
  __shared__ float tile[32][33];
  int bx = blockIdx.x * 32, by = blockIdx.y * 32;
  int tx = threadIdx.x, ty = threadIdx.y;   // (32, 8)
#pragma unroll
  for (int i = 0; i < 4; i++)
    tile[ty + 8*i][tx] = W[(size_t)(by + ty + 8*i) * DD + bx + tx];
  __syncthreads();
#pragma unroll
  for (int i = 0; i < 4; i++)
    O[(size_t)(bx + ty + 8*i) * DD + by + tx] = (_Float16)tile[tx][ty + 8*i];
}

// ---------------- GEMM: C[M][N] = A[M][K] * Bt[N][K]^T + bias ----------------
// 128x128 tile, BK=32, 4 waves (2x2 of 64x64), 16x16x32 fp16 MFMA.
// mode: 0 = fp16 plain (K), 1 = fp16 * QSCALE (Q), 2 = fp16 V^T per-head
//       ( out[((b*16+h)*64+d)*2048 + t] ), 3 = f32 plain (proj)
static __device__ __forceinline__ void gemm_body(
    const _Float16* __restrict__ A, const _Float16* __restrict__ Bt,
    const float* __restrict__ bias, void* __restrict__ Cv, int mode) {
  const int K = 1024, N = 1024;
  __shared__ __align__(16) _Float16 Alds[128*32];
  __shared__ __align__(16) _Float16 Blds[128*32];
  int tid = threadIdx.x;
  int wid = tid >> 6, lane = tid & 63;
  int m0 = blockIdx.y * 128, n0 = blockIdx.x * 128;
  int wr = wid >> 1, wc = wid & 1;
  int lr = lane & 15, lk = lane >> 4;

  f32x4 zf = {0.f, 0.f, 0.f, 0.f};
  f32x4 acc[4][4];
#pragma unroll
  for (int m = 0; m < 4; m++)
#pragma unroll
    for (int n = 0; n < 4; n++) acc[m][n] = zf;

  int c0 = wid * 2;
  int srow = c0 * 16 + (lane >> 2);
  int skc  = (lane & 3) * 8;
  const _Float16* gA0 = A  + (size_t)(m0 + srow) * K + skc;
  const _Float16* gA1 = gA0 + 16 * K;
  const _Float16* gB0 = Bt + (size_t)(n0 + srow) * K + skc;
  const _Float16* gB1 = gB0 + 16 * K;
  _Float16* lA0 = Alds + c0 * 512;
  _Float16* lA1 = Alds + (c0 + 1) * 512;
  _Float16* lB0 = Blds + c0 * 512;
  _Float16* lB1 = Blds + (c0 + 1) * 512;

  for (int k0 = 0; k0 < K; k0 += 32) {
    __syncthreads();
    gload_lds16(gA0 + k0, lA0);
    gload_lds16(gA1 + k0, lA1);
    gload_lds16(gB0 + k0, lB0);
    gload_lds16(gB1 + k0, lB1);
    __syncthreads();
    f16x8 af[4], bf[4];
#pragma unroll
    for (int m = 0; m < 4; m++)
      af[m] = *(const f16x8*)&Alds[(wr*64 + m*16 + lr)*32 + lk*8];
#pragma unroll
    for (int n = 0; n < 4; n++)
      bf[n] = *(const f16x8*)&Blds[(wc*64 + n*16 + lr)*32 + lk*8];
#pragma unroll
    for (int m = 0; m < 4; m++)
#pragma unroll
      for (int n = 0; n < 4; n++)
        acc[m][n] = __builtin_amdgcn_mfma_f32_16x16x32_f16(af[m], bf[n], acc[m][n], 0, 0, 0);
  }

  // epilogue: C/D layout col = lane&15, row = (lane>>4)*4 + r
#pragma unroll
  for (int n = 0; n < 4; n++) {
    int col = n0 + wc*64 + n*16 + lr;
    float bs = bias[col];
#pragma unroll
    for (int m = 0; m < 4; m++) {
      int rowg = m0 + wr*64 + m*16 + lk*4;
      if (mode == 2) {
        int b = rowg >> 11, t = rowg & 2047;
        size_t idx = ((size_t)(b*1024 + col) << 11) + t;
        f16x4 pk;
#pragma unroll
        for (int r = 0; r < 4; r++) pk[r] = (_Float16)(acc[m][n][r] + bs);
        *(f16x4*)&((_Float16*)Cv)[idx] = pk;
      } else if (mode == 3) {
#pragma unroll
        for (int r = 0; r < 4; r++)
          ((float*)Cv)[(size_t)(rowg + r) * N + col] = acc[m][n][r] + bs;
      } else if (mode == 1) {
#pragma unroll
        for (int r = 0; r < 4; r++)
          ((_Float16*)Cv)[(size_t)(rowg + r) * N + col] =
              (_Float16)((acc[m][n][r] + bs) * QSCALE);
      } else {
#pragma unroll
        for (int r = 0; r < 4; r++)
          ((_Float16*)Cv)[(size_t)(rowg + r) * N + col] = (_Float16)(acc[m][n][r] + bs);
      }
    }
  }
}

__global__ __launch_bounds__(256) void gemm_qkv(
    const _Float16* __restrict__ X,
    const _Float16* __restrict__ WqT, const _Float16* __restrict__ WkT,
    const _Float16* __restrict__ WvT,
    const float* __restrict__ bq, const float* __restrict__ bk,
    const float* __restrict__ bv,
    _Float16* __restrict__ Qo, _Float16* __restrict__ Ko, _Float16* __restrict__ Vto) {
  const _Float16* Bt; const float* bias; _Float16* C; int mode;
  if (blockIdx.z == 0)      { Bt = WqT; bias = bq; C = Qo;  mode = 1; }
  else if (blockIdx.z == 1) { Bt = WkT; bias = bk; C = Ko;  mode = 0; }
  else                      { Bt = WvT; bias = bv; C = Vto; mode = 2; }
  gemm_body(X, Bt, bias, C, mode);
}

__global__ __launch_bounds__(256) void gemm_proj(
    const _Float16* __restrict__ Ain, const _Float16* __restrict__ WpT,
    const float* __restrict__ bp, float* __restrict__ out) {
  gemm_body(Ain, WpT, bp, out, 3);
}

// ---------------- causal flash attention ----------------
// grid (8, 64), 256 threads = 4 waves; block handles q-tiles {bx, 15-bx} of 128
// rows each (wave: 32 rows = 2 frags) -> every block does exactly 34 KV tiles.
// KV tiles of 64, double-buffered; K and V^T both staged via global_load_lds +
// XOR chunk swizzle (identical proven mechanics).
__global__ __launch_bounds__(256, 3) void attn_fwd(
    const _Float16* __restrict__ Q, const _Float16* __restrict__ Kg,
    const _Float16* __restrict__ Vt, _Float16* __restrict__ O) {
  // K: [buf][row j 0..63][64], LDS[row][c] = K[row][c ^ (row&7)]
  __shared__ __align__(16) _Float16 Klds[2*4096];
  // V^T: [buf][row d 0..63][64], LDS[d][c] = V^T[d][c ^ (d&7)]
  __shared__ __align__(16) _Float16 Vlds[2*4096];
  // P: per-wave [32][72]
  __shared__ __align__(16) _Float16 Plds[4*32*72];

  const int tid = threadIdx.x;
  const int wid = tid >> 6, lane = tid & 63;
  const int lr = lane & 15, lk = lane >> 4;
  const int bh = blockIdx.y, b = bh >> 4, h = bh & 15;
  const size_t base  = (size_t)b * TT * DD + h * HD;   // Q/K/O layout [B,T,D]
  const size_t vbase = (size_t)bh * HD * TT;           // V^T layout [B,H,D_h,T]

  // staging: wave w covers rows 16w..16w+15 (2 calls of 8 rows);
  // lane L -> row (L>>3), lds chunk L&7, global chunk (L&7)^(L>>3).
  const int krow  = 16*wid + (lane >> 3);
  const int kchnk = ((lane & 7) ^ (lane >> 3)) * 8;
  const int kg0 = krow*DD + kchnk, kg1 = kg0 + 8*DD;
  const int vg0 = krow*TT + kchnk, vg1 = vg0 + 8*TT;
  const int kl0 = 16*wid*64,       kl1 = kl0 + 8*64;

  _Float16* Pw = Plds + wid*32*72;

  for (int qs = 0; qs < 2; ++qs) {
    const int qt = qs ? (15 - (int)blockIdx.x) : (int)blockIdx.x;
    const int jmax = 2*qt + 1;

    // Q fragments (pre-scaled by QSCALE at projection time)
    f16x8 qf[2][2];
#pragma unroll
    for (int t = 0; t < 2; ++t) {
      const size_t qr = base + (size_t)(qt*128 + wid*32 + t*16 + lr) * DD;
#pragma unroll
      for (int hh2 = 0; hh2 < 2; ++hh2)
        qf[t][hh2] = *(const f16x8*)&Q[qr + hh2*32 + lk*8];
    }

    f32x4 zf = {0.f, 0.f, 0.f, 0.f};
    f32x4 o[2][4];
    float m[2][4], l[2][4];
#pragma unroll
    for (int t = 0; t < 2; ++t)
#pragma unroll
      for (int f = 0; f < 4; ++f) o[t][f] = zf;
#pragma unroll
    for (int t = 0; t < 2; ++t)
#pragma unroll
      for (int r = 0; r < 4; ++r) { m[t][r] = -1e30f; l[t][r] = 0.f; }

    // ---- prologue: stage tile 0 into buf 0 ----
    gload_lds16(Kg + base + kg0, Klds + kl0);
    gload_lds16(Kg + base + kg1, Klds + kl1);
    gload_lds16(Vt + vbase + vg0, Vlds + kl0);
    gload_lds16(Vt + vbase + vg1, Vlds + kl1);
    __syncthreads();

    int bsel = 0;
    for (int jt = 0; jt <= jmax; ++jt) {
      if (jt < jmax) {   // issue next-tile async loads into alternate buffers
        const size_t kb = base + (size_t)(jt+1) * 64 * DD;
        const size_t vb = vbase + (size_t)(jt+1) * 64;
        _Float16* kd = Klds + (bsel^1)*4096;
        _Float16* vd = Vlds + (bsel^1)*4096;
        gload_lds16(Kg + kb + kg0, kd + kl0);
        gload_lds16(Kg + kb + kg1, kd + kl1);
        gload_lds16(Vt + vb + vg0, vd + kl0);
        gload_lds16(Vt + vb + vg1, vd + kl1);
      }

      // ---- QK^T ----
      const _Float16* Kb = Klds + bsel*4096;
      f32x4 s[2][4];
      __builtin_amdgcn_s_setprio(1);
#pragma unroll
      for (int f = 0; f < 4; ++f) {
        const int row = 16*f + lr;
        f16x8 kf0 = *(const f16x8*)&Kb[row*64 + ((lk    ) ^ (lr & 7))*8];
        f16x8 kf1 = *(const f16x8*)&Kb[row*64 + ((lk + 4) ^ (lr & 7))*8];
#pragma unroll
        for (int t = 0; t < 2; ++t) {
          f32x4 z = zf;
          z = __builtin_amdgcn_mfma_f32_16x16x32_f16(qf[t][0], kf0, z, 0, 0, 0);
          z = __builtin_amdgcn_mfma_f32_16x16x32_f16(qf[t][1], kf1, z, 0, 0, 0);
          s[t][f] = z;
        }
      }
      __builtin_amdgcn_s_setprio(0);

      // ---- causal mask (Q pre-scaled; mask is a pure select) ----
#pragma unroll
      for (int t = 0; t < 2; ++t) {
        const int qmin = qt*128 + wid*32 + t*16;
        if (64*jt + 64 > qmin) {
#pragma unroll
          for (int f = 0; f < 4; ++f)
#pragma unroll
            for (int r = 0; r < 4; ++r) {
              int jg = 64*jt + 16*f + lr;
              int qg = qmin + lk*4 + r;
              if (jg > qg) s[t][f][r] = -1e30f;
            }
        }
      }

      // ---- online softmax with defer-max (skip rescale unless max grew > 8) ----
      float vmax[2][4];
      bool grow = false;
#pragma unroll
      for (int t = 0; t < 2; ++t)
#pragma unroll
        for (int r = 0; r < 4; ++r) {
          float v = fmaxf(fmaxf(s[t][0][r], s[t][1][r]), fmaxf(s[t][2][r], s[t][3][r]));
          v = fmaxf(v, __shfl_xor(v, 1));
          v = fmaxf(v, __shfl_xor(v, 2));
          v = fmaxf(v, __shfl_xor(v, 4));
          v = fmaxf(v, __shfl_xor(v, 8));
          vmax[t][r] = v;
          grow = grow || (v > m[t][r] + 8.f);
        }
      const bool anygrow = (__ballot(grow) != 0ull);

#pragma unroll
      for (int t = 0; t < 2; ++t) {
#pragma unroll
        for (int r = 0; r < 4; ++r) {
          float alpha = 1.f;
          if (anygrow) {
            float mn = fmaxf(m[t][r], vmax[t][r]);
            alpha = exp2f(m[t][r] - mn);
            m[t][r] = mn;
          }
          float sum = 0.f;
#pragma unroll
          for (int f = 0; f < 4; ++f) {
            float p = exp2f(s[t][f][r] - m[t][r]);
            s[t][f][r] = p;
            sum += p;
          }
          sum += __shfl_xor(sum, 1);
          sum += __shfl_xor(sum, 2);
          sum += __shfl_xor(sum, 4);
          sum += __shfl_xor(sum, 8);
          l[t][r] = l[t][r] * alpha + sum;
          if (anygrow) {
#pragma unroll
            for (int f = 0; f < 4; ++f) o[t][f][r] *= alpha;
          }
        }
        // P -> per-wave LDS (C-layout -> A-frag layout)
#pragma unroll
        for (int f = 0; f < 4; ++f)
#pragma unroll
          for (int r = 0; r < 4; ++r)
            Pw[(t*16 + lk*4 + r)*72 + f*16 + lr] = (_Float16)s[t][f][r];
      }

      // ---- P A-frags ----
      f16x8 pa[2][2];
#pragma unroll
      for (int t = 0; t < 2; ++t)
#pragma unroll
        for (int hh2 = 0; hh2 < 2; ++hh2)
          pa[t][hh2] = *(const f16x8*)&Pw[(t*16 + lr)*72 + hh2*32 + lk*8];

      // ---- O += P V  (V B-frags mirror the K reads) ----
      const _Float16* Vb = Vlds + bsel*4096;
      __builtin_amdgcn_s_setprio(1);
#pragma unroll
      for (int f = 0; f < 4; ++f) {
        const int row = 16*f + lr;   // d index
        f16x8 vf0 = *(const f16x8*)&Vb[row*64 + ((lk    ) ^ (lr & 7))*8];
        f16x8 vf1 = *(const f16x8*)&Vb[row*64 + ((lk + 4) ^ (lr & 7))*8];
#pragma unroll
        for (int t = 0; t < 2; ++t) {
          o[t][f] = __builtin_amdgcn_mfma_f32_16x16x32_f16(pa[t][0], vf0, o[t][f], 0, 0, 0);
          o[t][f] = __builtin_amdgcn_mfma_f32_16x16x32_f16(pa[t][1], vf1, o[t][f], 0, 0, 0);
        }
      }
      __builtin_amdgcn_s_setprio(0);

      __syncthreads();   // drains async gloads into buf^1 + all LDS reads
      bsel ^= 1;
    }

    // ---- finalize + write O ----
#pragma unroll
    for (int t = 0; t < 2; ++t) {
      float inv[4];
#pragma unroll
      for (int r = 0; r < 4; ++r) inv[r] = 1.f / l[t][r];
#pragma unroll
      for (int f = 0; f < 4; ++f) {
        int d = 16*f + lr;
#pragma unroll
        for (int r = 0; r < 4; ++r) {
          int qg = qt*128 + wid*32 + t*16 + lk*4 + r;
          O[base + (size_t)qg * DD + d] = (_Float16)(o[t][f][r] * inv[r]);
        }
      }
    }
  }
}

extern "C" void kernel_launch(void* const* d_in, const int* in_sizes, int n_in,
                              void* d_out, int out_size, void* d_ws, size_t ws_size,
                              hipStream_t stream) {
  const float* x  = (const float*)d_in[0];
  const float* Wq = (const float*)d_in[1];
  const float* bq = (const float*)d_in[2];
  const float* Wk = (const float*)d_in[3];
  const float* bk = (const float*)d_in[4];
  const float* Wv = (const float*)d_in[5];
  const float* bv = (const float*)d_in[6];
  const float* Wp = (const float*)d_in[7];
  const float* bp = (const float*)d_in[8];
  float* out = (float*)d_out;

  const size_t XN = (size_t)MM * DD;   // 8,388,608
  const size_t WN = (size_t)DD * DD;   // 1,048,576
  _Float16* ws  = (_Float16*)d_ws;
  _Float16* Xb  = ws;                  // also reused as attention output (Ab)
  _Float16* WqT = ws + XN;
  _Float16* WkT = WqT + WN;
  _Float16* WvT = WkT + WN;
  _Float16* WpT = WvT + WN;
  _Float16* Qb  = WpT + WN;
  _Float16* Kb  = Qb + XN;
  _Float16* Vbt = Kb + XN;             // V^T [B,H,HD,T]
  _Float16* Ab  = Xb;

  cvt_f16<<<dim3((unsigned)(XN/8/256)), 256, 0, stream>>>(x, Xb, (int)(XN/8));
  transpose_cvt<<<dim3(32, 32, 4), dim3(32, 8), 0, stream>>>(Wq, Wk, Wv, Wp,
                                                             WqT, WkT, WvT, WpT);
  gemm_qkv<<<dim3(8, 64, 3), 256, 0, stream>>>(Xb, WqT, WkT, WvT, bq, bk, bv,
                                               Qb, Kb, Vbt);
  attn_fwd<<<dim3(8, 64), 256, 0, stream>>>(Qb, Kb, Vbt, Ab);
  gemm_proj<<<dim3(8, 64), 256, 0, stream>>>(Ab, WpT, bp, out);
}

// Round 8
// 293.691 us; speedup vs baseline: 1.5428x; 1.1998x over previous
//
#include <hip/hip_runtime.h>
#include <hip/hip_bf16.h>

#define BB 4
#define TT 2048
#define DD 1024
#define HH 16
#define HD 64
#define MM (BB*TT)   // 8192

typedef __attribute__((ext_vector_type(8))) _Float16 f16x8;
typedef __attribute__((ext_vector_type(4))) _Float16 f16x4;
typedef __attribute__((ext_vector_type(2))) _Float16 f16x2;
typedef __attribute__((ext_vector_type(4))) float f32x4;
typedef __attribute__((ext_vector_type(16))) float f32x16;
typedef __attribute__((ext_vector_type(4))) unsigned int u32x4;

// (1/sqrt(64)) * log2(e) — folded into Q at projection time
#define QSCALE 0.18033688011112042f

static __device__ __forceinline__ void gload_lds16(const void* g, void* l) {
  __builtin_amdgcn_global_load_lds((const __attribute__((address_space(1))) void*)g,
                                   (__attribute__((address_space(3))) void*)l, 16, 0, 0);
}

// ---------------- fp32 -> fp16 conversion, 8 elems/thread ----------------
__global__ __launch_bounds__(256) void cvt_f16(const float* __restrict__ in,
                                               _Float16* __restrict__ out, int n8) {
  int i = blockIdx.x * 256 + threadIdx.x;
  if (i >= n8) return;
  const f32x4* p = (const f32x4*)in;
  f32x4 a = p[2*i];
  f32x4 b = p[2*i+1];
  f16x8 r;
  r[0]=(_Float16)a[0]; r[1]=(_Float16)a[1]; r[2]=(_Float16)a[2]; r[3]=(_Float16)a[3];
  r[4]=(_Float16)b[0]; r[5]=(_Float16)b[1]; r[6]=(_Float16)b[2]; r[7]=(_Float16)b[3];
  *(f16x8*)(out + (size_t)8*i) = r;
}

// ------------- W[k][n] fp32 -> Wt[n][k] fp16 (1024x1024), z picks matrix -------------
__global__ __launch_bounds__(256) void transpose_cvt(
    const float* __restrict__ W0, const float* __restrict__ W1,
    const float* __restrict__ W2, const float* __restrict__ W3,
    _Float16* __restrict__ O0, _Float16* __restrict__ O1,
    _Float16* __restrict__ O2, _Float16* __restrict__ O3) {
  const float* W; _Float16* O;
  switch (blockIdx.z) {
    case 0: W = W0; O = O0; break;
    case 1: W = W1; O = O1; break;
    case 2: W = W2; O = O2; break;
    default: W = W3; O = O3; break;
  }
  __shared__ float tile[32][33];
  int bx = blockIdx.x * 32, by = blockIdx.y * 32;
  int tx = threadIdx.x, ty = threadIdx.y;   // (32, 8)
#pragma unroll
  for (int i = 0; i < 4; i++)
    tile[ty + 8*i][tx] = W[(size_t)(by + ty + 8*i) * DD + bx + tx];
  __syncthreads();
#pragma unroll
  for (int i = 0; i < 4; i++)
    O[(size_t)(bx + ty + 8*i) * DD + by + tx] = (_Float16)tile[tx][ty + 8*i];
}

// ---------------- GEMM: C[M][N] = A[M][K] * Bt[N][K]^T + bias ----------------
// 128x128 tile, BK=32, 4 waves (2x2 of 64x64), 16x16x32 fp16 MFMA.
// mode: 0 = fp16 plain (K), 1 = fp16 * QSCALE (Q), 2 = fp16 V^T per-head
//       ( out[((b*16+h)*64+d)*2048 + t] ), 3 = f32 plain (proj)
static __device__ __forceinline__ void gemm_body(
    const _Float16* __restrict__ A, const _Float16* __restrict__ Bt,
    const float* __restrict__ bias, void* __restrict__ Cv, int mode) {
  const int K = 1024, N = 1024;
  __shared__ __align__(16) _Float16 Alds[128*32];
  __shared__ __align__(16) _Float16 Blds[128*32];
  int tid = threadIdx.x;
  int wid = tid >> 6, lane = tid & 63;
  int m0 = blockIdx.y * 128, n0 = blockIdx.x * 128;
  int wr = wid >> 1, wc = wid & 1;
  int lr = lane & 15, lk = lane >> 4;

  f32x4 zf = {0.f, 0.f, 0.f, 0.f};
  f32x4 acc[4][4];
#pragma unroll
  for (int m = 0; m < 4; m++)
#pragma unroll
    for (int n = 0; n < 4; n++) acc[m][n] = zf;

  int c0 = wid * 2;
  int srow = c0 * 16 + (lane >> 2);
  int skc  = (lane & 3) * 8;
  const _Float16* gA0 = A  + (size_t)(m0 + srow) * K + skc;
  const _Float16* gA1 = gA0 + 16 * K;
  const _Float16* gB0 = Bt + (size_t)(n0 + srow) * K + skc;
  const _Float16* gB1 = gB0 + 16 * K;
  _Float16* lA0 = Alds + c0 * 512;
  _Float16* lA1 = Alds + (c0 + 1) * 512;
  _Float16* lB0 = Blds + c0 * 512;
  _Float16* lB1 = Blds + (c0 + 1) * 512;

  for (int k0 = 0; k0 < K; k0 += 32) {
    __syncthreads();
    gload_lds16(gA0 + k0, lA0);
    gload_lds16(gA1 + k0, lA1);
    gload_lds16(gB0 + k0, lB0);
    gload_lds16(gB1 + k0, lB1);
    __syncthreads();
    f16x8 af[4], bf[4];
#pragma unroll
    for (int m = 0; m < 4; m++)
      af[m] = *(const f16x8*)&Alds[(wr*64 + m*16 + lr)*32 + lk*8];
#pragma unroll
    for (int n = 0; n < 4; n++)
      bf[n] = *(const f16x8*)&Blds[(wc*64 + n*16 + lr)*32 + lk*8];
#pragma unroll
    for (int m = 0; m < 4; m++)
#pragma unroll
      for (int n = 0; n < 4; n++)
        acc[m][n] = __builtin_amdgcn_mfma_f32_16x16x32_f16(af[m], bf[n], acc[m][n], 0, 0, 0);
  }

  // epilogue: C/D layout col = lane&15, row = (lane>>4)*4 + r
#pragma unroll
  for (int n = 0; n < 4; n++) {
    int col = n0 + wc*64 + n*16 + lr;
    float bs = bias[col];
#pragma unroll
    for (int m = 0; m < 4; m++) {
      int rowg = m0 + wr*64 + m*16 + lk*4;
      if (mode == 2) {
        int b = rowg >> 11, t = rowg & 2047;
        size_t idx = ((size_t)(b*1024 + col) << 11) + t;
        f16x4 pk;
#pragma unroll
        for (int r = 0; r < 4; r++) pk[r] = (_Float16)(acc[m][n][r] + bs);
        *(f16x4*)&((_Float16*)Cv)[idx] = pk;
      } else if (mode == 3) {
#pragma unroll
        for (int r = 0; r < 4; r++)
          ((float*)Cv)[(size_t)(rowg + r) * N + col] = acc[m][n][r] + bs;
      } else if (mode == 1) {
#pragma unroll
        for (int r = 0; r < 4; r++)
          ((_Float16*)Cv)[(size_t)(rowg + r) * N + col] =
              (_Float16)((acc[m][n][r] + bs) * QSCALE);
      } else {
#pragma unroll
        for (int r = 0; r < 4; r++)
          ((_Float16*)Cv)[(size_t)(rowg + r) * N + col] = (_Float16)(acc[m][n][r] + bs);
      }
    }
  }
}

__global__ __launch_bounds__(256) void gemm_qkv(
    const _Float16* __restrict__ X,
    const _Float16* __restrict__ WqT, const _Float16* __restrict__ WkT,
    const _Float16* __restrict__ WvT,
    const float* __restrict__ bq, const float* __restrict__ bk,
    const float* __restrict__ bv,
    _Float16* __restrict__ Qo, _Float16* __restrict__ Ko, _Float16* __restrict__ Vto) {
  const _Float16* Bt; const float* bias; _Float16* C; int mode;
  if (blockIdx.z == 0)      { Bt = WqT; bias = bq; C = Qo;  mode = 1; }
  else if (blockIdx.z == 1) { Bt = WkT; bias = bk; C = Ko;  mode = 0; }
  else                      { Bt = WvT; bias = bv; C = Vto; mode = 2; }
  gemm_body(X, Bt, bias, C, mode);
}

__global__ __launch_bounds__(256) void gemm_proj(
    const _Float16* __restrict__ Ain, const _Float16* __restrict__ WpT,
    const float* __restrict__ bp, float* __restrict__ out) {
  gemm_body(Ain, WpT, bp, out, 3);
}

// ---------------- causal flash attention (32x32 swapped-QK^T) ----------------
// grid (8, 64), 256 threads = 4 waves; block handles q-tiles {bx, 15-bx} of 128
// rows (wave: 32 q-rows). KV tiles of 64, double-buffered; K and V^T staged via
// global_load_lds + XOR chunk swizzle (proven). S^T = mfma32x32(K, Q): lane owns
// col q=lane&31 -> in-register softmax; P repacked to A-frags with cvt_pkrtz +
// cross-half shfl_xor(32) exchange (no LDS for P).
__global__ __launch_bounds__(256, 2) void attn_fwd(
    const _Float16* __restrict__ Q, const _Float16* __restrict__ Kg,
    const _Float16* __restrict__ Vt, _Float16* __restrict__ O) {
  // K: [buf][j 0..63][64], slot c holds K[j][c ^ (j&7)] (pre-swizzled source)
  __shared__ __align__(16) char KldsB[2*8192];
  // V^T: [buf][d 0..63][64], slot c holds V^T[d][c ^ (d&7)]
  __shared__ __align__(16) char VldsB[2*8192];

  const int tid = threadIdx.x;
  const int wid = tid >> 6, lane = tid & 63;
  const int lq = lane & 31, hi = lane >> 5;
  const int bh = blockIdx.y, b = bh >> 4, h = bh & 15;
  const size_t base  = (size_t)b * TT * DD + h * HD;   // Q/K/O layout [B,T,D]
  const size_t vbase = (size_t)bh * HD * TT;           // V^T layout [B,H,D_h,T]

  // staging: wave w covers rows 16w..16w+15 (2 calls of 8 rows);
  // lane L -> row (L>>3), lds chunk L&7, global chunk (L&7)^(L>>3).
  const int srow  = 16*wid + (lane >> 3);
  const int schnk = ((lane & 7) ^ (lane >> 3)) * 8;
  const int kg0 = srow*DD + schnk, kg1 = kg0 + 8*DD;
  const int vg0 = srow*TT + schnk, vg1 = vg0 + 8*TT;
  const int sl0 = 16*wid*128,      sl1 = sl0 + 8*128;  // byte offsets

  for (int qs = 0; qs < 2; ++qs) {
    const int qt = qs ? (15 - (int)blockIdx.x) : (int)blockIdx.x;
    const int jmax = 2*qt + 1;
    const int wqmin = qt*128 + wid*32;
    const int wqmax = wqmin + 31;
    const int qg = wqmin + lq;           // this lane's q row (global)

    // Q B-frags (pre-scaled by QSCALE): lane holds Q[qg][kb*16 + hi*8 + 0..7]
    f16x8 qf[4];
    {
      const _Float16* qp = Q + base + (size_t)qg * DD + hi*8;
#pragma unroll
      for (int kb = 0; kb < 4; ++kb)
        qf[kb] = *(const f16x8*)(qp + kb*16);
    }

    f32x16 o0, o1;
#pragma unroll
    for (int r = 0; r < 16; ++r) { o0[r] = 0.f; o1[r] = 0.f; }
    float m = -1e30f, l = 0.f;

    // ---- prologue: stage tile 0 into buf 0 ----
    gload_lds16(Kg + base + kg0, KldsB + sl0);
    gload_lds16(Kg + base + kg1, KldsB + sl1);
    gload_lds16(Vt + vbase + vg0, VldsB + sl0);
    gload_lds16(Vt + vbase + vg1, VldsB + sl1);
    __syncthreads();

    int bsel = 0;
    for (int jt = 0; jt <= jmax; ++jt) {
      if (jt < jmax) {   // issue next-tile async loads into alternate buffers
        const size_t kb_ = base + (size_t)(jt+1) * 64 * DD;
        const size_t vb_ = vbase + (size_t)(jt+1) * 64;
        char* kd = KldsB + (bsel^1)*8192;
        char* vd = VldsB + (bsel^1)*8192;
        gload_lds16(Kg + kb_ + kg0, kd + sl0);
        gload_lds16(Kg + kb_ + kg1, kd + sl1);
        gload_lds16(Vt + vb_ + vg0, vd + sl0);
        gload_lds16(Vt + vb_ + vg1, vd + sl1);
      }

      const bool use0 = (jt*64      <= wqmax);
      const bool use1 = (jt*64 + 32 <= wqmax);

      if (use0) {
        const char* Kb = KldsB + bsel*8192;
        const char* Vb = VldsB + bsel*8192;
        f32x16 st[2];

        // ---- S^T = K · Q^T  (A = K rows j, B = Q cols q) ----
        __builtin_amdgcn_s_setprio(1);
#pragma unroll
        for (int jb = 0; jb < 2; ++jb) {
          if (jb == 1 && !use1) break;
          const int jrow = jb*32 + lq;
          f32x16 z;
#pragma unroll
          for (int r = 0; r < 16; ++r) z[r] = 0.f;
#pragma unroll
          for (int kb = 0; kb < 4; ++kb) {
            f16x8 kf = *(const f16x8*)(Kb + jrow*128 + (((kb*2 + hi) ^ (lq & 7))*16));
            z = __builtin_amdgcn_mfma_f32_32x32x16_f16(kf, qf[kb], z, 0, 0, 0);
          }
          st[jb] = z;
        }
        __builtin_amdgcn_s_setprio(0);

        // ---- causal mask (S^T row j = crow(r,hi), col q = lq) ----
#pragma unroll
        for (int jb = 0; jb < 2; ++jb) {
          if (jb == 1 && !use1) break;
          const int jbase = jt*64 + jb*32;
          if (jbase + 31 > wqmin) {
#pragma unroll
            for (int r = 0; r < 16; ++r) {
              int jg = jbase + (r & 3) + ((r >> 2) << 3) + (hi << 2);
              if (jg > qg) st[jb][r] = -1e30f;
            }
          }
        }

        // ---- in-register online softmax (defer-max THR=8) ----
        float pm = -1e30f;
#pragma unroll
        for (int r = 0; r < 16; ++r) pm = fmaxf(pm, st[0][r]);
        if (use1) {
#pragma unroll
          for (int r = 0; r < 16; ++r) pm = fmaxf(pm, st[1][r]);
        }
        pm = fmaxf(pm, __shfl_xor(pm, 32));
        const bool grow = (pm > m + 8.f);
        const bool anygrow = (__ballot(grow) != 0ull);
        float alpha = 1.f;
        if (anygrow) {
          float mn = fmaxf(m, pm);
          alpha = exp2f(m - mn);
          m = mn;
        }
        float rs = 0.f;
#pragma unroll
        for (int r = 0; r < 16; ++r) {
          float p = exp2f(st[0][r] - m);
          st[0][r] = p;
          rs += p;
        }
        if (use1) {
#pragma unroll
          for (int r = 0; r < 16; ++r) {
            float p = exp2f(st[1][r] - m);
            st[1][r] = p;
            rs += p;
          }
        }
        rs += __shfl_xor(rs, 32);
        l = l * alpha + rs;
        if (anygrow) {
#pragma unroll
          for (int r = 0; r < 16; ++r) {
            float ar = __shfl(alpha, (r & 3) + ((r >> 2) << 3) + (hi << 2));
            o0[r] *= ar;
            o1[r] *= ar;
          }
        }

        // ---- pack P into A-frags: cvt_pkrtz + cross-half exchange ----
        // lane (q=lq,hi) holds, per kb2-half, words x0..x3 = P at j-local
        // {0,1},{2,3},{8,9},{10,11} (+4*hi, +16*kb2). A-frag needs words
        // w0..w3 = j-local {8hi+0..7} (+16*kb2):
        //   hi=0: {x0, x1, px0, px1}   hi=1: {px2, px3, x2, x3}
        // where px* = partner(lane^32)'s x*. Exchange via give-away select +
        // shfl_xor(32) + take-back select (semantics unambiguous).
        f16x8 pa[2][2];
#pragma unroll
        for (int jb = 0; jb < 2; ++jb) {
          if (jb == 1 && !use1) break;
#pragma unroll
          for (int kb2 = 0; kb2 < 2; ++kb2) {
            const int s0 = kb2*8;
            unsigned x0 = __builtin_bit_cast(unsigned,
                __builtin_amdgcn_cvt_pkrtz(st[jb][s0+0], st[jb][s0+1]));
            unsigned x1 = __builtin_bit_cast(unsigned,
                __builtin_amdgcn_cvt_pkrtz(st[jb][s0+2], st[jb][s0+3]));
            unsigned x2 = __builtin_bit_cast(unsigned,
                __builtin_amdgcn_cvt_pkrtz(st[jb][s0+4], st[jb][s0+5]));
            unsigned x3 = __builtin_bit_cast(unsigned,
                __builtin_amdgcn_cvt_pkrtz(st[jb][s0+6], st[jb][s0+7]));
            unsigned g0 = hi ? x0 : x2;               // value given to partner
            unsigned g1 = hi ? x1 : x3;
            unsigned pg0 = (unsigned)__shfl_xor((int)g0, 32);
            unsigned pg1 = (unsigned)__shfl_xor((int)g1, 32);
            unsigned w0 = hi ? pg0 : x0;              // j {8hi+0,8hi+1}
            unsigned w1 = hi ? pg1 : x1;              // j {8hi+2,8hi+3}
            unsigned w2 = hi ? x2 : pg0;              // j {8hi+4,8hi+5}
            unsigned w3 = hi ? x3 : pg1;              // j {8hi+6,8hi+7}
            pa[jb][kb2] = __builtin_bit_cast(f16x8, (u32x4){w0, w1, w2, w3});
          }
        }

        // ---- O += P · V  (B-frags from V^T, mirror K reads) ----
        __builtin_amdgcn_s_setprio(1);
#pragma unroll
        for (int db = 0; db < 2; ++db) {
          const int drow = db*32 + lq;
          f32x16* op = db ? &o1 : &o0;
#pragma unroll
          for (int jb = 0; jb < 2; ++jb) {
            if (jb == 1 && !use1) break;
#pragma unroll
            for (int kb2 = 0; kb2 < 2; ++kb2) {
              const int jc = jb*4 + kb2*2 + hi;
              f16x8 vf = *(const f16x8*)(Vb + drow*128 + ((jc ^ (lq & 7))*16));
              *op = __builtin_amdgcn_mfma_f32_32x32x16_f16(pa[jb][kb2], vf, *op, 0, 0, 0);
            }
          }
        }
        __builtin_amdgcn_s_setprio(0);
      }

      __syncthreads();   // drains async gloads into buf^1 + all LDS reads
      bsel ^= 1;
    }

    // ---- finalize + write O (o[db][r] = O[q=crow(r,hi)][d=db*32+lq]) ----
    float inv = 1.f / l;
#pragma unroll
    for (int r = 0; r < 16; ++r) {
      float ir = __shfl(inv, (r & 3) + ((r >> 2) << 3) + (hi << 2));
      int qr = qt*128 + wid*32 + (r & 3) + ((r >> 2) << 3) + (hi << 2);
      _Float16* dst = O + base + (size_t)qr * DD + lq;
      dst[0]  = (_Float16)(o0[r] * ir);
      dst[32] = (_Float16)(o1[r] * ir);
    }
  }
}

extern "C" void kernel_launch(void* const* d_in, const int* in_sizes, int n_in,
                              void* d_out, int out_size, void* d_ws, size_t ws_size,
                              hipStream_t stream) {
  const float* x  = (const float*)d_in[0];
  const float* Wq = (const float*)d_in[1];
  const float* bq = (const float*)d_in[2];
  const float* Wk = (const float*)d_in[3];
  const float* bk = (const float*)d_in[4];
  const float* Wv = (const float*)d_in[5];
  const float* bv = (const float*)d_in[6];
  const float* Wp = (const float*)d_in[7];
  const float* bp = (const float*)d_in[8];
  float* out = (float*)d_out;

  const size_t XN = (size_t)MM * DD;   // 8,388,608
  const size_t WN = (size_t)DD * DD;   // 1,048,576
  _Float16* ws  = (_Float16*)d_ws;
  _Float16* Xb  = ws;                  // also reused as attention output (Ab)
  _Float16* WqT = ws + XN;
  _Float16* WkT = WqT + WN;
  _Float16* WvT = WkT + WN;
  _Float16* WpT = WvT + WN;
  _Float16* Qb  = WpT + WN;
  _Float16* Kb  = Qb + XN;
  _Float16* Vbt = Kb + XN;             // V^T [B,H,HD,T]
  _Float16* Ab  = Xb;

  cvt_f16<<<dim3((unsigned)(XN/8/256)), 256, 0, stream>>>(x, Xb, (int)(XN/8));
  transpose_cvt<<<dim3(32, 32, 4), dim3(32, 8), 0, stream>>>(Wq, Wk, Wv, Wp,
                                                             WqT, WkT, WvT, WpT);
  gemm_qkv<<<dim3(8, 64, 3), 256, 0, stream>>>(Xb, WqT, WkT, WvT, bq, bk, bv,
                                               Qb, Kb, Vbt);
  attn_fwd<<<dim3(8, 64), 256, 0, stream>>>(Qb, Kb, Vbt, Ab);
  gemm_proj<<<dim3(8, 64), 256, 0, stream>>>(Ab, WpT, bp, out);
}